// Round 7
// baseline (2370.553 us; speedup 1.0000x reference)
//
#include <hip/hip_runtime.h>
#include <math.h>

#define N_USERS 50000
#define N_ITEMS 50000
#define N_NODES 100000
#define NNZ_E   1600000
#define EMB     64
#define BATCH   4096
#define REG_C   1e-5f

// bucketed geometry
#define BSH    8                                  // 256 rows per bucket
#define NBUCK  ((N_NODES + 255) >> BSH)           // 391
#define BCAP   5120                               // mean 4096 + 16 sigma slack
#define NSB    256                                // binning blocks
#define CHUNK  ((NNZ_E + NSB - 1) / NSB)          // 6250 edges per block

__device__ __forceinline__ unsigned short f2bf(float f) {
    unsigned u = __float_as_uint(f);
    u = (u + 0x7FFFu + ((u >> 16) & 1u)) >> 16;   // round-to-nearest-even
    return (unsigned short)u;
}
__device__ __forceinline__ float bf2f(unsigned short h) {
    return __uint_as_float(((unsigned)h) << 16);
}

// ---------------------------------------------------------------------------
// ego = concat(user_emb, item_emb), plus bf16 shadow for the SpMM gather
// ---------------------------------------------------------------------------
__global__ __launch_bounds__(256) void init_ego(const float* __restrict__ ue,
                                                const float* __restrict__ ie,
                                                float* __restrict__ ego,
                                                unsigned short* __restrict__ ego16) {
    const int total = N_NODES * EMB / 4;      // float4 count
    const int uf4   = N_USERS * EMB / 4;
    for (int idx = blockIdx.x * blockDim.x + threadIdx.x; idx < total;
         idx += gridDim.x * blockDim.x) {
        float4 v = (idx < uf4) ? ((const float4*)ue)[idx]
                               : ((const float4*)ie)[idx - uf4];
        ((float4*)ego)[idx] = v;
        ushort4 h;
        h.x = f2bf(v.x); h.y = f2bf(v.y); h.z = f2bf(v.z); h.w = f2bf(v.w);
        *(ushort4*)&ego16[(size_t)idx * 4] = h;
    }
}

// ---------------------------------------------------------------------------
// Pass 1: bin edges by 256-row bucket. Per-block LDS histogram, one atomic
// reservation per (block,bucket), contiguous run writes.
// bin entry: ( (row&255)<<17 | col , val_bits )
// ---------------------------------------------------------------------------
__global__ __launch_bounds__(256) void binscatter(const int* __restrict__ rw,
                                                  const int* __restrict__ cl,
                                                  const float* __restrict__ val,
                                                  int* __restrict__ bcnt,
                                                  int2* __restrict__ bin) {
    __shared__ int lcount[NBUCK];
    __shared__ int lbase[NBUCK];
    const int t    = threadIdx.x;
    const int eend = min(NNZ_E, (int)((blockIdx.x + 1) * CHUNK));

    for (int b = t; b < NBUCK; b += 256) lcount[b] = 0;
    __syncthreads();

    for (int e = blockIdx.x * CHUNK + t; e < eend; e += 256)
        atomicAdd(&lcount[rw[e] >> BSH], 1);
    __syncthreads();

    for (int b = t; b < NBUCK; b += 256) {
        const int c = lcount[b];
        lbase[b]  = (c > 0) ? atomicAdd(&bcnt[b], c) : 0;
        lcount[b] = 0;
    }
    __syncthreads();

    for (int e = blockIdx.x * CHUNK + t; e < eend; e += 256) {
        const int r = rw[e];
        const int b = r >> BSH;
        const int ofs = atomicAdd(&lcount[b], 1);
        const int rel = lbase[b] + ofs;
        if (rel < BCAP)
            bin[(size_t)b * BCAP + rel] =
                make_int2(((r & 255) << 17) | cl[e], __float_as_int(val[e]));
    }
}

// ---------------------------------------------------------------------------
// Pass 2: per-bucket counting sort by col>>9 (in place via LDS staging).
// Sorted col order gives cross-block temporal locality for the SpMM gather.
// ---------------------------------------------------------------------------
__global__ __launch_bounds__(256) void colsort_place(const int* __restrict__ bcnt,
                                                     int2* __restrict__ bin) {
    __shared__ int2 ebuf[BCAP];          // 40 KB
    __shared__ int  cnt[256];
    __shared__ int  wt[4];
    const int t    = threadIdx.x;
    const int buck = blockIdx.x;
    const int n    = min(bcnt[buck], BCAP);
    int2* mybin = bin + (size_t)buck * BCAP;

    cnt[t] = 0;
    for (int i = t; i < n; i += 256) ebuf[i] = mybin[i];
    __syncthreads();

    for (int i = t; i < n; i += 256)
        atomicAdd(&cnt[(ebuf[i].x & 0x1FFFF) >> 9], 1);   // key 0..195
    __syncthreads();

    const int c    = cnt[t];
    const int lane = t & 63, w = t >> 6;
    int incl = c;
    #pragma unroll
    for (int off = 1; off < 64; off <<= 1) {
        const int v = __shfl_up(incl, off);
        if (lane >= off) incl += v;
    }
    if (lane == 63) wt[w] = incl;
    __syncthreads();
    int wb = 0;
    #pragma unroll
    for (int q = 0; q < 4; ++q) wb += (q < w) ? wt[q] : 0;
    cnt[t] = wb + incl - c;              // exclusive base per key
    __syncthreads();

    for (int i = t; i < n; i += 256) {
        const int2 e   = ebuf[i];
        const int  pos = atomicAdd(&cnt[(e.x & 0x1FFFF) >> 9], 1);
        mybin[pos] = e;
    }
}

// ---------------------------------------------------------------------------
// Bucket SpMM: one 512-thread block per 256-row bucket, 64 KB LDS f32 acc.
// Waves sweep col-sorted edge stripes -> gathers stay L2-resident.
// ---------------------------------------------------------------------------
__global__ __launch_bounds__(512) void spmm_bucket(const int* __restrict__ bcnt,
                                                   const int2* __restrict__ ep,
                                                   const unsigned short* __restrict__ xb,
                                                   float* __restrict__ y) {
    __shared__ float acc[256 * EMB];     // 64 KB
    const int t    = threadIdx.x;
    const int lane = t & 63;
    const int w    = t >> 6;             // wave 0..7
    const int buck = blockIdx.x;
    const int n    = min(bcnt[buck], BCAP);
    const int2* mye = ep + (size_t)buck * BCAP;

    for (int i = t; i < 256 * EMB / 4; i += 512)
        ((float4*)acc)[i] = make_float4(0.f, 0.f, 0.f, 0.f);
    __syncthreads();

    int e = (n * w) >> 3;
    const int eend = (n * (w + 1)) >> 3;
    for (; e + 8 <= eend; e += 8) {
        int2  p[8];
        float xv[8];
        #pragma unroll
        for (int q = 0; q < 8; ++q) p[q] = mye[e + q];
        #pragma unroll
        for (int q = 0; q < 8; ++q)
            xv[q] = bf2f(xb[(size_t)(p[q].x & 0x1FFFF) * EMB + lane]);
        #pragma unroll
        for (int q = 0; q < 8; ++q)
            atomicAdd(&acc[((p[q].x >> 17) << 6) + lane],
                      __int_as_float(p[q].y) * xv[q]);
    }
    for (; e < eend; ++e) {
        const int2 p = mye[e];
        atomicAdd(&acc[((p.x >> 17) << 6) + lane],
                  __int_as_float(p.y) * bf2f(xb[(size_t)(p.x & 0x1FFFF) * EMB + lane]));
    }
    __syncthreads();

    const int rbase = buck << 8;
    for (int i = t; i < 256 * EMB / 4; i += 512) {
        const int row = rbase + (i >> 4);
        if (row < N_NODES)
            ((float4*)y)[((size_t)rbase << 4) + i] = ((const float4*)acc)[i];
    }
}

// ---------------------------------------------------------------------------
// Fused: ego = leaky_relu(side @ Wgc + bgc + (ego*(side-ego)) @ Wbi + bbi)
// Also refreshes the bf16 shadow of ego.
// ---------------------------------------------------------------------------
__global__ __launch_bounds__(256) void layer_update(const float* __restrict__ side,
                                                    float* __restrict__ ego,
                                                    unsigned short* __restrict__ ego16,
                                                    const float* __restrict__ Wgc,
                                                    const float* __restrict__ bgc,
                                                    const float* __restrict__ Wbi,
                                                    const float* __restrict__ bbi) {
    __shared__ float HT[EMB * EMB];   // HT[d][r^sw]  (h = side)
    __shared__ float GT[EMB * EMB];   // GT[d][r^sw]  (g = ego*(side-ego))
    __shared__ float WG[EMB * EMB];   // WG[d][o]
    __shared__ float WB[EMB * EMB];   // WB[d][o]

    const int t  = threadIdx.x;
    const int r0 = blockIdx.x * 64;

    #pragma unroll
    for (int it = 0; it < 4; ++it) {
        const int f4  = t + it * 256;          // 0..1023
        const int d   = f4 >> 4;               // W row / tile row
        const int c0  = (f4 & 15) * 4;         // starting col

        float4 wg = ((const float4*)Wgc)[f4];
        float4 wb = ((const float4*)Wbi)[f4];
        *(float4*)&WG[d * EMB + c0] = wg;
        *(float4*)&WB[d * EMB + c0] = wb;

        const int gr = r0 + d;
        float4 s4 = make_float4(0.f, 0.f, 0.f, 0.f);
        float4 e4 = s4;
        if (gr < N_NODES) {
            s4 = ((const float4*)side)[gr * 16 + (f4 & 15)];
            e4 = ((const float4*)ego)[gr * 16 + (f4 & 15)];
        }
        const float hv[4] = {s4.x, s4.y, s4.z, s4.w};
        const float ev[4] = {e4.x, e4.y, e4.z, e4.w};
        #pragma unroll
        for (int q = 0; q < 4; ++q) {
            const int dd = c0 + q;
            const int sw = (dd & 7) << 2;
            HT[dd * EMB + (d ^ sw)] = hv[q];
            GT[dd * EMB + (d ^ sw)] = ev[q] * (hv[q] - ev[q]);
        }
    }
    __syncthreads();

    const int tr = t >> 4;
    const int to = t & 15;

    float acc[4][4];
    #pragma unroll
    for (int i2 = 0; i2 < 4; ++i2)
        #pragma unroll
        for (int j2 = 0; j2 < 4; ++j2) acc[i2][j2] = 0.f;

    #pragma unroll 8
    for (int d = 0; d < EMB; ++d) {
        const int sw = (d & 7) << 2;
        const float4 ah4 = *(const float4*)&HT[d * EMB + ((tr * 4) ^ sw)];
        const float4 ag4 = *(const float4*)&GT[d * EMB + ((tr * 4) ^ sw)];
        const float4 wg4 = *(const float4*)&WG[d * EMB + to * 4];
        const float4 wb4 = *(const float4*)&WB[d * EMB + to * 4];
        const float ah[4] = {ah4.x, ah4.y, ah4.z, ah4.w};
        const float ag[4] = {ag4.x, ag4.y, ag4.z, ag4.w};
        const float wg[4] = {wg4.x, wg4.y, wg4.z, wg4.w};
        const float wb[4] = {wb4.x, wb4.y, wb4.z, wb4.w};
        #pragma unroll
        for (int i2 = 0; i2 < 4; ++i2)
            #pragma unroll
            for (int j2 = 0; j2 < 4; ++j2)
                acc[i2][j2] += ah[i2] * wg[j2] + ag[i2] * wb[j2];
    }

    const float4 bg4 = ((const float4*)bgc)[to];
    const float4 bb4 = ((const float4*)bbi)[to];
    const float bs[4] = {bg4.x + bb4.x, bg4.y + bb4.y, bg4.z + bb4.z, bg4.w + bb4.w};

    #pragma unroll
    for (int i2 = 0; i2 < 4; ++i2) {
        const int gr = r0 + tr * 4 + i2;
        if (gr < N_NODES) {
            float4 vo;
            float* vp = (float*)&vo;
            #pragma unroll
            for (int j2 = 0; j2 < 4; ++j2) {
                float v = acc[i2][j2] + bs[j2];
                vp[j2] = (v >= 0.f) ? v : 0.01f * v;
            }
            *(float4*)&ego[gr * EMB + to * 4] = vo;
            ushort4 h;
            h.x = f2bf(vo.x); h.y = f2bf(vo.y); h.z = f2bf(vo.z); h.w = f2bf(vo.w);
            *(ushort4*)&ego16[(size_t)gr * EMB + to * 4] = h;
        }
    }
}

// ---------------------------------------------------------------------------
// gather + per-row L2 normalize for the 3*BATCH needed rows of this layer
// ---------------------------------------------------------------------------
__global__ __launch_bounds__(256) void gather_norm(const float* __restrict__ ego,
                                                   const int* __restrict__ u,
                                                   const int* __restrict__ ii,
                                                   const int* __restrict__ jj,
                                                   float* __restrict__ Gk) {
    const int gtid = blockIdx.x * blockDim.x + threadIdx.x;
    const int wave = gtid >> 6;
    const int lane = threadIdx.x & 63;
    if (wave >= 3 * BATCH) return;
    const int a = wave / BATCH;
    const int b = wave - a * BATCH;
    const int node = (a == 0) ? u[b] : N_USERS + ((a == 1) ? ii[b] : jj[b]);
    const float v = ego[(size_t)node * EMB + lane];
    float ss = v * v;
    #pragma unroll
    for (int m = 32; m; m >>= 1) ss += __shfl_xor(ss, m);
    const float inv = 1.f / fmaxf(sqrtf(ss), 1e-12f);
    Gk[(size_t)wave * EMB + lane] = v * inv;
}

// ---------------------------------------------------------------------------
// BPR loss + L2 reg  (one wave per sample)
// ---------------------------------------------------------------------------
__global__ __launch_bounds__(256) void loss_kernel(const float* __restrict__ ue,
                                                   const float* __restrict__ ie,
                                                   const float* __restrict__ G,
                                                   const int* __restrict__ u,
                                                   const int* __restrict__ ii,
                                                   const int* __restrict__ jj,
                                                   float* __restrict__ out) {
    const int gtid = blockIdx.x * blockDim.x + threadIdx.x;
    const int b    = gtid >> 6;
    const int lane = threadIdx.x & 63;
    if (b >= BATCH) return;

    const int uu = u[b], pi = ii[b], nj = jj[b];
    float uv[4], pv[4], nv[4];
    uv[0] = ue[(size_t)uu * EMB + lane];
    pv[0] = ie[(size_t)pi * EMB + lane];
    nv[0] = ie[(size_t)nj * EMB + lane];
    #pragma unroll
    for (int k = 0; k < 3; ++k) {
        uv[k + 1] = G[(((size_t)k * 3 + 0) * BATCH + b) * EMB + lane];
        pv[k + 1] = G[(((size_t)k * 3 + 1) * BATCH + b) * EMB + lane];
        nv[k + 1] = G[(((size_t)k * 3 + 2) * BATCH + b) * EMB + lane];
    }
    float yui = 0.f, yuj = 0.f, l2 = 0.f;
    #pragma unroll
    for (int s = 0; s < 4; ++s) {
        yui += uv[s] * pv[s];
        yuj += uv[s] * nv[s];
        l2  += uv[s] * uv[s] + pv[s] * pv[s] + nv[s] * nv[s];
    }
    #pragma unroll
    for (int m = 32; m; m >>= 1) {
        yui += __shfl_xor(yui, m);
        yuj += __shfl_xor(yuj, m);
        l2  += __shfl_xor(l2, m);
    }
    if (lane == 0) {
        const float d  = yui - yuj;
        const float sp = (d > 0.f) ? log1pf(expf(-d)) : (-d + log1pf(expf(d)));
        const float contrib = sp * (1.f / BATCH) + REG_C * (l2 * 0.5f) * (1.f / BATCH);
        atomicAdd(out, contrib);
    }
}

// ---------------------------------------------------------------------------
extern "C" void kernel_launch(void* const* d_in, const int* in_sizes, int n_in,
                              void* d_out, int out_size, void* d_ws, size_t ws_size,
                              hipStream_t stream) {
    const float* ue   = (const float*)d_in[0];
    const float* ie   = (const float*)d_in[1];
    const float* Wgc  = (const float*)d_in[2];
    const float* bgc  = (const float*)d_in[3];
    const float* Wbi  = (const float*)d_in[4];
    const float* bbi  = (const float*)d_in[5];
    const float* aval = (const float*)d_in[6];
    const int*   arow = (const int*)d_in[7];
    const int*   acol = (const int*)d_in[8];
    const int*   u    = (const int*)d_in[9];
    const int*   ii   = (const int*)d_in[10];
    const int*   jj   = (const int*)d_in[11];
    float* out = (float*)d_out;

    const size_t NE = (size_t)N_NODES * EMB;            // 6.4M floats
    char* p = (char*)d_ws;
    float* ego   = (float*)p;                 p += NE * 4;                      // 25.6 MB
    float* sideb = (float*)p;                 p += NE * 4;                      // 25.6 MB
    float* G     = (float*)p;                 p += (size_t)9 * BATCH * EMB * 4; // 9.4 MB
    int* bcnt    = (int*)p;                   p += (size_t)(NBUCK + 1) * 4;
    p = (char*)(((uintptr_t)p + 15) & ~(uintptr_t)15);
    int2* bin    = (int2*)p;                  p += (size_t)NBUCK * BCAP * 8;    // 16.0 MB
    p = (char*)(((uintptr_t)p + 15) & ~(uintptr_t)15);
    unsigned short* ego16 = (unsigned short*)p;                                 // 12.8 MB

    // ---- build bucketed, col-sorted edge lists once ----------------------
    hipMemsetAsync(bcnt, 0, (NBUCK + 1) * sizeof(int), stream);
    hipLaunchKernelGGL(binscatter, dim3(NSB), dim3(256), 0, stream,
                       arow, acol, aval, bcnt, bin);
    hipLaunchKernelGGL(colsort_place, dim3(NBUCK), dim3(256), 0, stream,
                       bcnt, bin);

    hipLaunchKernelGGL(init_ego, dim3(2048), dim3(256), 0, stream, ue, ie, ego, ego16);

    for (int k = 0; k < 3; ++k) {
        hipLaunchKernelGGL(spmm_bucket, dim3(NBUCK), dim3(512), 0, stream,
                           bcnt, bin, ego16, sideb);
        hipLaunchKernelGGL(layer_update, dim3((N_NODES + 63) / 64), dim3(256), 0, stream,
                           sideb, ego, ego16,
                           Wgc + (size_t)k * EMB * EMB, bgc + (size_t)k * EMB,
                           Wbi + (size_t)k * EMB * EMB, bbi + (size_t)k * EMB);
        hipLaunchKernelGGL(gather_norm, dim3((3 * BATCH + 3) / 4), dim3(256), 0, stream,
                           ego, u, ii, jj, G + (size_t)k * 3 * BATCH * EMB);
    }

    hipMemsetAsync(d_out, 0, sizeof(float), stream);
    hipLaunchKernelGGL(loss_kernel, dim3(BATCH / 4), dim3(256), 0, stream,
                       ue, ie, G, u, ii, jj, out);
}

// Round 8
// 513.602 us; speedup vs baseline: 4.6155x; 4.6155x over previous
//
#include <hip/hip_runtime.h>
#include <math.h>

#define N_USERS 50000
#define N_ITEMS 50000
#define N_NODES 100000
#define NNZ_E   1600000
#define EMB     64
#define BATCH   4096
#define REG_C   1e-5f

// bucketed geometry
#define BSH    8                                  // 256 rows per bucket
#define NBUCK  ((N_NODES + 255) >> BSH)           // 391
#define BCAP   5120                               // mean 4096 + 16 sigma slack
#define NSB    256                                // binning blocks
#define CHUNK  ((NNZ_E + NSB - 1) / NSB)          // 6250 edges per block

__device__ __forceinline__ unsigned short f2bf(float f) {
    unsigned u = __float_as_uint(f);
    u = (u + 0x7FFFu + ((u >> 16) & 1u)) >> 16;   // round-to-nearest-even
    return (unsigned short)u;
}
__device__ __forceinline__ float bf2f(unsigned short h) {
    return __uint_as_float(((unsigned)h) << 16);
}

// ---------------------------------------------------------------------------
// ego16 = bf16(concat(user_emb, item_emb))
// ---------------------------------------------------------------------------
__global__ __launch_bounds__(256) void init_ego(const float* __restrict__ ue,
                                                const float* __restrict__ ie,
                                                unsigned short* __restrict__ ego16) {
    const int total = N_NODES * EMB / 4;      // float4 count
    const int uf4   = N_USERS * EMB / 4;
    for (int idx = blockIdx.x * blockDim.x + threadIdx.x; idx < total;
         idx += gridDim.x * blockDim.x) {
        float4 v = (idx < uf4) ? ((const float4*)ue)[idx]
                               : ((const float4*)ie)[idx - uf4];
        ushort4 h;
        h.x = f2bf(v.x); h.y = f2bf(v.y); h.z = f2bf(v.z); h.w = f2bf(v.w);
        *(ushort4*)&ego16[(size_t)idx * 4] = h;
    }
}

// ---------------------------------------------------------------------------
// Pass 1: bin edges by 256-row bucket. Per-block LDS histogram, one atomic
// reservation per (block,bucket), contiguous run writes.
// bin entry: ( (row&255)<<17 | col , val_bits )
// ---------------------------------------------------------------------------
__global__ __launch_bounds__(256) void binscatter(const int* __restrict__ rw,
                                                  const int* __restrict__ cl,
                                                  const float* __restrict__ val,
                                                  int* __restrict__ bcnt,
                                                  int2* __restrict__ bin) {
    __shared__ int lcount[NBUCK];
    __shared__ int lbase[NBUCK];
    const int t    = threadIdx.x;
    const int eend = min(NNZ_E, (int)((blockIdx.x + 1) * CHUNK));

    for (int b = t; b < NBUCK; b += 256) lcount[b] = 0;
    __syncthreads();

    for (int e = blockIdx.x * CHUNK + t; e < eend; e += 256)
        atomicAdd(&lcount[rw[e] >> BSH], 1);
    __syncthreads();

    for (int b = t; b < NBUCK; b += 256) {
        const int c = lcount[b];
        lbase[b]  = (c > 0) ? atomicAdd(&bcnt[b], c) : 0;
        lcount[b] = 0;
    }
    __syncthreads();

    for (int e = blockIdx.x * CHUNK + t; e < eend; e += 256) {
        const int r = rw[e];
        const int b = r >> BSH;
        const int ofs = atomicAdd(&lcount[b], 1);
        const int rel = lbase[b] + ofs;
        if (rel < BCAP)
            bin[(size_t)b * BCAP + rel] =
                make_int2(((r & 255) << 17) | cl[e], __float_as_int(val[e]));
    }
}

// ---------------------------------------------------------------------------
// Exclusive scan of the 391 bucket counts
// ---------------------------------------------------------------------------
__global__ __launch_bounds__(512) void scan_buckets(const int* __restrict__ bcnt,
                                                    int* __restrict__ bbase) {
    const int t = threadIdx.x;
    const int lane = t & 63, w = t >> 6;
    const int v = (t < NBUCK) ? bcnt[t] : 0;
    int incl = v;
    #pragma unroll
    for (int off = 1; off < 64; off <<= 1) {
        const int x = __shfl_up(incl, off);
        if (lane >= off) incl += x;
    }
    __shared__ int wt[8];
    if (lane == 63) wt[w] = incl;
    __syncthreads();
    int wb = 0;
    #pragma unroll
    for (int q = 0; q < 8; ++q) wb += (q < w) ? wt[q] : 0;
    if (t < NBUCK) bbase[t] = wb + incl - v;
}

// ---------------------------------------------------------------------------
// Pass 2a: per-bucket counting sort by col>>9 (in place via LDS staging).
// Gives per-row approx col-ascending order downstream -> synchronized col
// sweep in the SpMM -> L2-resident gather bands.  (validated round 7)
// ---------------------------------------------------------------------------
__global__ __launch_bounds__(256) void colsort_place(const int* __restrict__ bcnt,
                                                     int2* __restrict__ bin) {
    __shared__ int2 ebuf[BCAP];          // 40 KB
    __shared__ int  cnt[256];
    __shared__ int  wt[4];
    const int t    = threadIdx.x;
    const int buck = blockIdx.x;
    const int n    = min(bcnt[buck], BCAP);
    int2* mybin = bin + (size_t)buck * BCAP;

    cnt[t] = 0;
    for (int i = t; i < n; i += 256) ebuf[i] = mybin[i];
    __syncthreads();

    for (int i = t; i < n; i += 256)
        atomicAdd(&cnt[(ebuf[i].x & 0x1FFFF) >> 9], 1);   // key 0..195
    __syncthreads();

    const int c    = cnt[t];
    const int lane = t & 63, w = t >> 6;
    int incl = c;
    #pragma unroll
    for (int off = 1; off < 64; off <<= 1) {
        const int v = __shfl_up(incl, off);
        if (lane >= off) incl += v;
    }
    if (lane == 63) wt[w] = incl;
    __syncthreads();
    int wb = 0;
    #pragma unroll
    for (int q = 0; q < 4; ++q) wb += (q < w) ? wt[q] : 0;
    cnt[t] = wb + incl - c;              // exclusive base per key
    __syncthreads();

    for (int i = t; i < n; i += 256) {
        const int2 e   = ebuf[i];
        const int  pos = atomicAdd(&cnt[(e.x & 0x1FFFF) >> 9], 1);
        mybin[pos] = e;
    }
}

// ---------------------------------------------------------------------------
// Pass 2b: one block per bucket, place edges at exact CSR positions.
// Iterating the col-sorted bin keeps per-row lists approx col-ascending.
// ---------------------------------------------------------------------------
__global__ __launch_bounds__(256) void csr_place(const int* __restrict__ bcnt,
                                                 const int* __restrict__ bbase,
                                                 const int2* __restrict__ bin,
                                                 int* __restrict__ row_ptr,
                                                 int2* __restrict__ ep) {
    __shared__ int rcnt[256];
    __shared__ int rbase[256];
    __shared__ int wt[4];
    const int t    = threadIdx.x;
    const int buck = blockIdx.x;
    const int n    = min(bcnt[buck], BCAP);
    const int base = bbase[buck];
    const int2* mybin = bin + (size_t)buck * BCAP;

    rcnt[t] = 0;
    __syncthreads();
    for (int i = t; i < n; i += 256)
        atomicAdd(&rcnt[mybin[i].x >> 17], 1);
    __syncthreads();

    const int c = rcnt[t];
    const int lane = t & 63, w = t >> 6;
    int incl = c;
    #pragma unroll
    for (int off = 1; off < 64; off <<= 1) {
        const int x = __shfl_up(incl, off);
        if (lane >= off) incl += x;
    }
    if (lane == 63) wt[w] = incl;
    __syncthreads();
    int wb = 0;
    #pragma unroll
    for (int q = 0; q < 4; ++q) wb += (q < w) ? wt[q] : 0;
    const int myb = base + wb + incl - c;

    const int gr = (buck << BSH) + t;
    if (gr < N_NODES) row_ptr[gr] = myb;
    if (buck == 0 && t == 0) row_ptr[N_NODES] = NNZ_E;
    rbase[t] = myb;
    __syncthreads();
    rcnt[t] = 0;
    __syncthreads();

    for (int i = t; i < n; i += 256) {
        const int2 e  = mybin[i];
        const int r8  = e.x >> 17;
        const int col = e.x & 0x1FFFF;
        const int ofs = atomicAdd(&rcnt[r8], 1);
        ep[rbase[r8] + ofs] = make_int2(col, e.y);
    }
}

// ---------------------------------------------------------------------------
// CSR SpMM, bf16 in / bf16 out: one wave per row, lane = emb dim, f32 acc,
// 8-deep gather unroll for MLP. Edge pack loads are wave-uniform broadcasts.
// ---------------------------------------------------------------------------
__global__ __launch_bounds__(256) void spmm_csr(const int* __restrict__ rp,
                                                const int2* __restrict__ ep,
                                                const unsigned short* __restrict__ xb,
                                                unsigned short* __restrict__ y16) {
    const int w    = (blockIdx.x * blockDim.x + threadIdx.x) >> 6;
    const int lane = threadIdx.x & 63;
    if (w >= N_NODES) return;
    const int beg = rp[w];
    const int end = rp[w + 1];
    float acc = 0.f;
    int e = beg;
    for (; e + 8 <= end; e += 8) {
        int2  p[8];
        float xv[8];
        #pragma unroll
        for (int q = 0; q < 8; ++q) p[q] = ep[e + q];
        #pragma unroll
        for (int q = 0; q < 8; ++q)
            xv[q] = bf2f(xb[(size_t)p[q].x * EMB + lane]);
        #pragma unroll
        for (int q = 0; q < 8; ++q)
            acc += __int_as_float(p[q].y) * xv[q];
    }
    for (; e + 4 <= end; e += 4) {
        int2  p[4];
        float xv[4];
        #pragma unroll
        for (int q = 0; q < 4; ++q) p[q] = ep[e + q];
        #pragma unroll
        for (int q = 0; q < 4; ++q)
            xv[q] = bf2f(xb[(size_t)p[q].x * EMB + lane]);
        #pragma unroll
        for (int q = 0; q < 4; ++q)
            acc += __int_as_float(p[q].y) * xv[q];
    }
    for (; e < end; ++e) {
        const int2 p = ep[e];
        acc += __int_as_float(p.y) * bf2f(xb[(size_t)p.x * EMB + lane]);
    }
    y16[(size_t)w * EMB + lane] = f2bf(acc);
}

// ---------------------------------------------------------------------------
// Fused: ego = leaky_relu(side @ Wgc + bgc + (ego*(side-ego)) @ Wbi + bbi)
// bf16 in (side16, ego16), bf16 out (ego16). f32 LDS tiles + f32 math.
// ---------------------------------------------------------------------------
__global__ __launch_bounds__(256) void layer_update(const unsigned short* __restrict__ side16,
                                                    unsigned short* __restrict__ ego16,
                                                    const float* __restrict__ Wgc,
                                                    const float* __restrict__ bgc,
                                                    const float* __restrict__ Wbi,
                                                    const float* __restrict__ bbi) {
    __shared__ float HT[EMB * EMB];   // HT[d][r^sw]  (h = side)
    __shared__ float GT[EMB * EMB];   // GT[d][r^sw]  (g = ego*(side-ego))
    __shared__ float WG[EMB * EMB];   // WG[d][o]
    __shared__ float WB[EMB * EMB];   // WB[d][o]

    const int t  = threadIdx.x;
    const int r0 = blockIdx.x * 64;

    #pragma unroll
    for (int it = 0; it < 4; ++it) {
        const int f4  = t + it * 256;          // 0..1023
        const int d   = f4 >> 4;               // W row / tile row
        const int c0  = (f4 & 15) * 4;         // starting col

        float4 wg = ((const float4*)Wgc)[f4];
        float4 wb = ((const float4*)Wbi)[f4];
        *(float4*)&WG[d * EMB + c0] = wg;
        *(float4*)&WB[d * EMB + c0] = wb;

        const int gr = r0 + d;
        float hv[4] = {0.f, 0.f, 0.f, 0.f};
        float ev[4] = {0.f, 0.f, 0.f, 0.f};
        if (gr < N_NODES) {
            const ushort4 s4h = *(const ushort4*)&side16[(size_t)gr * EMB + c0];
            const ushort4 e4h = *(const ushort4*)&ego16[(size_t)gr * EMB + c0];
            hv[0] = bf2f(s4h.x); hv[1] = bf2f(s4h.y); hv[2] = bf2f(s4h.z); hv[3] = bf2f(s4h.w);
            ev[0] = bf2f(e4h.x); ev[1] = bf2f(e4h.y); ev[2] = bf2f(e4h.z); ev[3] = bf2f(e4h.w);
        }
        #pragma unroll
        for (int q = 0; q < 4; ++q) {
            const int dd = c0 + q;
            const int sw = (dd & 7) << 2;
            HT[dd * EMB + (d ^ sw)] = hv[q];
            GT[dd * EMB + (d ^ sw)] = ev[q] * (hv[q] - ev[q]);
        }
    }
    __syncthreads();

    const int tr = t >> 4;
    const int to = t & 15;

    float acc[4][4];
    #pragma unroll
    for (int i2 = 0; i2 < 4; ++i2)
        #pragma unroll
        for (int j2 = 0; j2 < 4; ++j2) acc[i2][j2] = 0.f;

    #pragma unroll 8
    for (int d = 0; d < EMB; ++d) {
        const int sw = (d & 7) << 2;
        const float4 ah4 = *(const float4*)&HT[d * EMB + ((tr * 4) ^ sw)];
        const float4 ag4 = *(const float4*)&GT[d * EMB + ((tr * 4) ^ sw)];
        const float4 wg4 = *(const float4*)&WG[d * EMB + to * 4];
        const float4 wb4 = *(const float4*)&WB[d * EMB + to * 4];
        const float ah[4] = {ah4.x, ah4.y, ah4.z, ah4.w};
        const float ag[4] = {ag4.x, ag4.y, ag4.z, ag4.w};
        const float wg[4] = {wg4.x, wg4.y, wg4.z, wg4.w};
        const float wb[4] = {wb4.x, wb4.y, wb4.z, wb4.w};
        #pragma unroll
        for (int i2 = 0; i2 < 4; ++i2)
            #pragma unroll
            for (int j2 = 0; j2 < 4; ++j2)
                acc[i2][j2] += ah[i2] * wg[j2] + ag[i2] * wb[j2];
    }

    const float4 bg4 = ((const float4*)bgc)[to];
    const float4 bb4 = ((const float4*)bbi)[to];
    const float bs[4] = {bg4.x + bb4.x, bg4.y + bb4.y, bg4.z + bb4.z, bg4.w + bb4.w};

    #pragma unroll
    for (int i2 = 0; i2 < 4; ++i2) {
        const int gr = r0 + tr * 4 + i2;
        if (gr < N_NODES) {
            ushort4 h;
            float v0 = acc[i2][0] + bs[0];
            float v1 = acc[i2][1] + bs[1];
            float v2 = acc[i2][2] + bs[2];
            float v3 = acc[i2][3] + bs[3];
            v0 = (v0 >= 0.f) ? v0 : 0.01f * v0;
            v1 = (v1 >= 0.f) ? v1 : 0.01f * v1;
            v2 = (v2 >= 0.f) ? v2 : 0.01f * v2;
            v3 = (v3 >= 0.f) ? v3 : 0.01f * v3;
            h.x = f2bf(v0); h.y = f2bf(v1); h.z = f2bf(v2); h.w = f2bf(v3);
            *(ushort4*)&ego16[(size_t)gr * EMB + to * 4] = h;
        }
    }
}

// ---------------------------------------------------------------------------
// gather + per-row L2 normalize for the 3*BATCH needed rows of this layer
// ---------------------------------------------------------------------------
__global__ __launch_bounds__(256) void gather_norm(const unsigned short* __restrict__ ego16,
                                                   const int* __restrict__ u,
                                                   const int* __restrict__ ii,
                                                   const int* __restrict__ jj,
                                                   float* __restrict__ Gk) {
    const int gtid = blockIdx.x * blockDim.x + threadIdx.x;
    const int wave = gtid >> 6;
    const int lane = threadIdx.x & 63;
    if (wave >= 3 * BATCH) return;
    const int a = wave / BATCH;
    const int b = wave - a * BATCH;
    const int node = (a == 0) ? u[b] : N_USERS + ((a == 1) ? ii[b] : jj[b]);
    const float v = bf2f(ego16[(size_t)node * EMB + lane]);
    float ss = v * v;
    #pragma unroll
    for (int m = 32; m; m >>= 1) ss += __shfl_xor(ss, m);
    const float inv = 1.f / fmaxf(sqrtf(ss), 1e-12f);
    Gk[(size_t)wave * EMB + lane] = v * inv;
}

// ---------------------------------------------------------------------------
// BPR loss + L2 reg  (one wave per sample)
// ---------------------------------------------------------------------------
__global__ __launch_bounds__(256) void loss_kernel(const float* __restrict__ ue,
                                                   const float* __restrict__ ie,
                                                   const float* __restrict__ G,
                                                   const int* __restrict__ u,
                                                   const int* __restrict__ ii,
                                                   const int* __restrict__ jj,
                                                   float* __restrict__ out) {
    const int gtid = blockIdx.x * blockDim.x + threadIdx.x;
    const int b    = gtid >> 6;
    const int lane = threadIdx.x & 63;
    if (b >= BATCH) return;

    const int uu = u[b], pi = ii[b], nj = jj[b];
    float uv[4], pv[4], nv[4];
    uv[0] = ue[(size_t)uu * EMB + lane];
    pv[0] = ie[(size_t)pi * EMB + lane];
    nv[0] = ie[(size_t)nj * EMB + lane];
    #pragma unroll
    for (int k = 0; k < 3; ++k) {
        uv[k + 1] = G[(((size_t)k * 3 + 0) * BATCH + b) * EMB + lane];
        pv[k + 1] = G[(((size_t)k * 3 + 1) * BATCH + b) * EMB + lane];
        nv[k + 1] = G[(((size_t)k * 3 + 2) * BATCH + b) * EMB + lane];
    }
    float yui = 0.f, yuj = 0.f, l2 = 0.f;
    #pragma unroll
    for (int s = 0; s < 4; ++s) {
        yui += uv[s] * pv[s];
        yuj += uv[s] * nv[s];
        l2  += uv[s] * uv[s] + pv[s] * pv[s] + nv[s] * nv[s];
    }
    #pragma unroll
    for (int m = 32; m; m >>= 1) {
        yui += __shfl_xor(yui, m);
        yuj += __shfl_xor(yuj, m);
        l2  += __shfl_xor(l2, m);
    }
    if (lane == 0) {
        const float d  = yui - yuj;
        const float sp = (d > 0.f) ? log1pf(expf(-d)) : (-d + log1pf(expf(d)));
        const float contrib = sp * (1.f / BATCH) + REG_C * (l2 * 0.5f) * (1.f / BATCH);
        atomicAdd(out, contrib);
    }
}

// ---------------------------------------------------------------------------
extern "C" void kernel_launch(void* const* d_in, const int* in_sizes, int n_in,
                              void* d_out, int out_size, void* d_ws, size_t ws_size,
                              hipStream_t stream) {
    const float* ue   = (const float*)d_in[0];
    const float* ie   = (const float*)d_in[1];
    const float* Wgc  = (const float*)d_in[2];
    const float* bgc  = (const float*)d_in[3];
    const float* Wbi  = (const float*)d_in[4];
    const float* bbi  = (const float*)d_in[5];
    const float* aval = (const float*)d_in[6];
    const int*   arow = (const int*)d_in[7];
    const int*   acol = (const int*)d_in[8];
    const int*   u    = (const int*)d_in[9];
    const int*   ii   = (const int*)d_in[10];
    const int*   jj   = (const int*)d_in[11];
    float* out = (float*)d_out;

    const size_t NE = (size_t)N_NODES * EMB;            // 6.4M elements
    char* p = (char*)d_ws;
    unsigned short* ego16  = (unsigned short*)p;  p += NE * 2;                  // 12.8 MB
    unsigned short* side16 = (unsigned short*)p;  p += NE * 2;                  // 12.8 MB
    float* G     = (float*)p;                 p += (size_t)9 * BATCH * EMB * 4; // 9.4 MB
    int* row_ptr = (int*)p;                   p += (size_t)(N_NODES + 2) * 4;
    int* bcnt    = (int*)p;                   p += (size_t)(NBUCK + 1) * 4;
    int* bbase   = (int*)p;                   p += (size_t)(NBUCK + 1) * 4;
    p = (char*)(((uintptr_t)p + 15) & ~(uintptr_t)15);
    int2* epack  = (int2*)p;                  p += (size_t)NNZ_E * 8;           // 12.8 MB
    int2* bin    = (int2*)p;                  p += (size_t)NBUCK * BCAP * 8;    // 16.0 MB

    // ---- build bucketed, col-sorted CSR once -----------------------------
    hipMemsetAsync(bcnt, 0, (NBUCK + 1) * sizeof(int), stream);
    hipLaunchKernelGGL(binscatter, dim3(NSB), dim3(256), 0, stream,
                       arow, acol, aval, bcnt, bin);
    hipLaunchKernelGGL(scan_buckets, dim3(1), dim3(512), 0, stream, bcnt, bbase);
    hipLaunchKernelGGL(colsort_place, dim3(NBUCK), dim3(256), 0, stream,
                       bcnt, bin);
    hipLaunchKernelGGL(csr_place, dim3(NBUCK), dim3(256), 0, stream,
                       bcnt, bbase, bin, row_ptr, epack);

    hipLaunchKernelGGL(init_ego, dim3(2048), dim3(256), 0, stream, ue, ie, ego16);

    for (int k = 0; k < 3; ++k) {
        hipLaunchKernelGGL(spmm_csr, dim3((N_NODES * 64 + 255) / 256), dim3(256), 0, stream,
                           row_ptr, epack, ego16, side16);
        hipLaunchKernelGGL(layer_update, dim3((N_NODES + 63) / 64), dim3(256), 0, stream,
                           side16, ego16,
                           Wgc + (size_t)k * EMB * EMB, bgc + (size_t)k * EMB,
                           Wbi + (size_t)k * EMB * EMB, bbi + (size_t)k * EMB);
        hipLaunchKernelGGL(gather_norm, dim3((3 * BATCH + 3) / 4), dim3(256), 0, stream,
                           ego16, u, ii, jj, G + (size_t)k * 3 * BATCH * EMB);
    }

    hipMemsetAsync(d_out, 0, sizeof(float), stream);
    hipLaunchKernelGGL(loss_kernel, dim3(BATCH / 4), dim3(256), 0, stream,
                       ue, ie, G, u, ii, jj, out);
}

// Round 10
// 477.782 us; speedup vs baseline: 4.9616x; 1.0750x over previous
//
#include <hip/hip_runtime.h>
#include <math.h>

#define N_USERS 50000
#define N_ITEMS 50000
#define N_NODES 100000
#define NNZ_E   1600000
#define EMB     64
#define BATCH   4096
#define REG_C   1e-5f

// bucketed geometry
#define BSH    8                                  // 256 rows per bucket
#define NBUCK  ((N_NODES + 255) >> BSH)           // 391
#define BCAP   5120                               // mean 4096 + 16 sigma slack
#define NSB    256                                // binning blocks
#define CHUNK  ((NNZ_E + NSB - 1) / NSB)          // 6250 edges per block

// loss reduction geometry
#define LNB    256                                // partial blocks
#define LSPB   (BATCH / LNB)                      // 16 samples per block

__device__ __forceinline__ unsigned short f2bf(float f) {
    unsigned u = __float_as_uint(f);
    u = (u + 0x7FFFu + ((u >> 16) & 1u)) >> 16;   // round-to-nearest-even
    return (unsigned short)u;
}
__device__ __forceinline__ float bf2f(unsigned short h) {
    return __uint_as_float(((unsigned)h) << 16);
}

// ---------------------------------------------------------------------------
// ego16 = bf16(concat(user_emb, item_emb))
// ---------------------------------------------------------------------------
__global__ __launch_bounds__(256) void init_ego(const float* __restrict__ ue,
                                                const float* __restrict__ ie,
                                                unsigned short* __restrict__ ego16) {
    const int total = N_NODES * EMB / 4;      // float4 count
    const int uf4   = N_USERS * EMB / 4;
    for (int idx = blockIdx.x * blockDim.x + threadIdx.x; idx < total;
         idx += gridDim.x * blockDim.x) {
        float4 v = (idx < uf4) ? ((const float4*)ue)[idx]
                               : ((const float4*)ie)[idx - uf4];
        ushort4 h;
        h.x = f2bf(v.x); h.y = f2bf(v.y); h.z = f2bf(v.z); h.w = f2bf(v.w);
        *(ushort4*)&ego16[(size_t)idx * 4] = h;
    }
}

// ---------------------------------------------------------------------------
// Pass 1: bin edges by 256-row bucket.
// bin entry: ( (row&255)<<17 | col , val_bits )
// ---------------------------------------------------------------------------
__global__ __launch_bounds__(256) void binscatter(const int* __restrict__ rw,
                                                  const int* __restrict__ cl,
                                                  const float* __restrict__ val,
                                                  int* __restrict__ bcnt,
                                                  int2* __restrict__ bin) {
    __shared__ int lcount[NBUCK];
    __shared__ int lbase[NBUCK];
    const int t    = threadIdx.x;
    const int eend = min(NNZ_E, (int)((blockIdx.x + 1) * CHUNK));

    for (int b = t; b < NBUCK; b += 256) lcount[b] = 0;
    __syncthreads();

    for (int e = blockIdx.x * CHUNK + t; e < eend; e += 256)
        atomicAdd(&lcount[rw[e] >> BSH], 1);
    __syncthreads();

    for (int b = t; b < NBUCK; b += 256) {
        const int c = lcount[b];
        lbase[b]  = (c > 0) ? atomicAdd(&bcnt[b], c) : 0;
        lcount[b] = 0;
    }
    __syncthreads();

    for (int e = blockIdx.x * CHUNK + t; e < eend; e += 256) {
        const int r = rw[e];
        const int b = r >> BSH;
        const int ofs = atomicAdd(&lcount[b], 1);
        const int rel = lbase[b] + ofs;
        if (rel < BCAP)
            bin[(size_t)b * BCAP + rel] =
                make_int2(((r & 255) << 17) | cl[e], __float_as_int(val[e]));
    }
}

// ---------------------------------------------------------------------------
// Exclusive scan of the 391 bucket counts
// ---------------------------------------------------------------------------
__global__ __launch_bounds__(512) void scan_buckets(const int* __restrict__ bcnt,
                                                    int* __restrict__ bbase) {
    const int t = threadIdx.x;
    const int lane = t & 63, w = t >> 6;
    const int v = (t < NBUCK) ? bcnt[t] : 0;
    int incl = v;
    #pragma unroll
    for (int off = 1; off < 64; off <<= 1) {
        const int x = __shfl_up(incl, off);
        if (lane >= off) incl += x;
    }
    __shared__ int wt[8];
    if (lane == 63) wt[w] = incl;
    __syncthreads();
    int wb = 0;
    #pragma unroll
    for (int q = 0; q < 8; ++q) wb += (q < w) ? wt[q] : 0;
    if (t < NBUCK) bbase[t] = wb + incl - v;
}

// ---------------------------------------------------------------------------
// Pass 2a: per-bucket counting sort by col>>9 (L2 gather locality)
// ---------------------------------------------------------------------------
__global__ __launch_bounds__(256) void colsort_place(const int* __restrict__ bcnt,
                                                     int2* __restrict__ bin) {
    __shared__ int2 ebuf[BCAP];          // 40 KB
    __shared__ int  cnt[256];
    __shared__ int  wt[4];
    const int t    = threadIdx.x;
    const int buck = blockIdx.x;
    const int n    = min(bcnt[buck], BCAP);
    int2* mybin = bin + (size_t)buck * BCAP;

    cnt[t] = 0;
    for (int i = t; i < n; i += 256) ebuf[i] = mybin[i];
    __syncthreads();

    for (int i = t; i < n; i += 256)
        atomicAdd(&cnt[(ebuf[i].x & 0x1FFFF) >> 9], 1);   // key 0..195
    __syncthreads();

    const int c    = cnt[t];
    const int lane = t & 63, w = t >> 6;
    int incl = c;
    #pragma unroll
    for (int off = 1; off < 64; off <<= 1) {
        const int v = __shfl_up(incl, off);
        if (lane >= off) incl += v;
    }
    if (lane == 63) wt[w] = incl;
    __syncthreads();
    int wb = 0;
    #pragma unroll
    for (int q = 0; q < 4; ++q) wb += (q < w) ? wt[q] : 0;
    cnt[t] = wb + incl - c;              // exclusive base per key
    __syncthreads();

    for (int i = t; i < n; i += 256) {
        const int2 e   = ebuf[i];
        const int  pos = atomicAdd(&cnt[(e.x & 0x1FFFF) >> 9], 1);
        mybin[pos] = e;
    }
}

// ---------------------------------------------------------------------------
// Pass 2b: place edges at exact CSR positions (col-sorted within rows)
// ---------------------------------------------------------------------------
__global__ __launch_bounds__(256) void csr_place(const int* __restrict__ bcnt,
                                                 const int* __restrict__ bbase,
                                                 const int2* __restrict__ bin,
                                                 int* __restrict__ row_ptr,
                                                 int2* __restrict__ ep) {
    __shared__ int rcnt[256];
    __shared__ int rbase[256];
    __shared__ int wt[4];
    const int t    = threadIdx.x;
    const int buck = blockIdx.x;
    const int n    = min(bcnt[buck], BCAP);
    const int base = bbase[buck];
    const int2* mybin = bin + (size_t)buck * BCAP;

    rcnt[t] = 0;
    __syncthreads();
    for (int i = t; i < n; i += 256)
        atomicAdd(&rcnt[mybin[i].x >> 17], 1);
    __syncthreads();

    const int c = rcnt[t];
    const int lane = t & 63, w = t >> 6;
    int incl = c;
    #pragma unroll
    for (int off = 1; off < 64; off <<= 1) {
        const int x = __shfl_up(incl, off);
        if (lane >= off) incl += x;
    }
    if (lane == 63) wt[w] = incl;
    __syncthreads();
    int wb = 0;
    #pragma unroll
    for (int q = 0; q < 4; ++q) wb += (q < w) ? wt[q] : 0;
    const int myb = base + wb + incl - c;

    const int gr = (buck << BSH) + t;
    if (gr < N_NODES) row_ptr[gr] = myb;
    if (buck == 0 && t == 0) row_ptr[N_NODES] = NNZ_E;
    rbase[t] = myb;
    __syncthreads();
    rcnt[t] = 0;
    __syncthreads();

    for (int i = t; i < n; i += 256) {
        const int2 e  = mybin[i];
        const int r8  = e.x >> 17;
        const int col = e.x & 0x1FFFF;
        const int ofs = atomicAdd(&rcnt[r8], 1);
        ep[rbase[r8] + ofs] = make_int2(col, e.y);
    }
}

// ---------------------------------------------------------------------------
// CSR SpMM, bf16 in / bf16 out: one wave per row, lane = emb dim, f32 acc
// ---------------------------------------------------------------------------
__global__ __launch_bounds__(256) void spmm_csr(const int* __restrict__ rp,
                                                const int2* __restrict__ ep,
                                                const unsigned short* __restrict__ xb,
                                                unsigned short* __restrict__ y16) {
    const int w    = (blockIdx.x * blockDim.x + threadIdx.x) >> 6;
    const int lane = threadIdx.x & 63;
    if (w >= N_NODES) return;
    const int beg = rp[w];
    const int end = rp[w + 1];
    float acc = 0.f;
    int e = beg;
    for (; e + 8 <= end; e += 8) {
        int2  p[8];
        float xv[8];
        #pragma unroll
        for (int q = 0; q < 8; ++q) p[q] = ep[e + q];
        #pragma unroll
        for (int q = 0; q < 8; ++q)
            xv[q] = bf2f(xb[(size_t)p[q].x * EMB + lane]);
        #pragma unroll
        for (int q = 0; q < 8; ++q)
            acc += __int_as_float(p[q].y) * xv[q];
    }
    for (; e + 4 <= end; e += 4) {
        int2  p[4];
        float xv[4];
        #pragma unroll
        for (int q = 0; q < 4; ++q) p[q] = ep[e + q];
        #pragma unroll
        for (int q = 0; q < 4; ++q)
            xv[q] = bf2f(xb[(size_t)p[q].x * EMB + lane]);
        #pragma unroll
        for (int q = 0; q < 4; ++q)
            acc += __int_as_float(p[q].y) * xv[q];
    }
    for (; e < end; ++e) {
        const int2 p = ep[e];
        acc += __int_as_float(p.y) * bf2f(xb[(size_t)p.x * EMB + lane]);
    }
    y16[(size_t)w * EMB + lane] = f2bf(acc);
}

// ---------------------------------------------------------------------------
// Fused: ego = leaky_relu(side @ Wgc + bgc + (ego*(side-ego)) @ Wbi + bbi)
// bf16 in/out, f32 LDS tiles + f32 math.
// ---------------------------------------------------------------------------
__global__ __launch_bounds__(256) void layer_update(const unsigned short* __restrict__ side16,
                                                    unsigned short* __restrict__ ego16,
                                                    const float* __restrict__ Wgc,
                                                    const float* __restrict__ bgc,
                                                    const float* __restrict__ Wbi,
                                                    const float* __restrict__ bbi) {
    __shared__ float HT[EMB * EMB];   // HT[d][r^sw]  (h = side)
    __shared__ float GT[EMB * EMB];   // GT[d][r^sw]  (g = ego*(side-ego))
    __shared__ float WG[EMB * EMB];   // WG[d][o]
    __shared__ float WB[EMB * EMB];   // WB[d][o]

    const int t  = threadIdx.x;
    const int r0 = blockIdx.x * 64;

    #pragma unroll
    for (int it = 0; it < 4; ++it) {
        const int f4  = t + it * 256;          // 0..1023
        const int d   = f4 >> 4;               // W row / tile row
        const int c0  = (f4 & 15) * 4;         // starting col

        float4 wg = ((const float4*)Wgc)[f4];
        float4 wb = ((const float4*)Wbi)[f4];
        *(float4*)&WG[d * EMB + c0] = wg;
        *(float4*)&WB[d * EMB + c0] = wb;

        const int gr = r0 + d;
        float hv[4] = {0.f, 0.f, 0.f, 0.f};
        float ev[4] = {0.f, 0.f, 0.f, 0.f};
        if (gr < N_NODES) {
            const ushort4 s4h = *(const ushort4*)&side16[(size_t)gr * EMB + c0];
            const ushort4 e4h = *(const ushort4*)&ego16[(size_t)gr * EMB + c0];
            hv[0] = bf2f(s4h.x); hv[1] = bf2f(s4h.y); hv[2] = bf2f(s4h.z); hv[3] = bf2f(s4h.w);
            ev[0] = bf2f(e4h.x); ev[1] = bf2f(e4h.y); ev[2] = bf2f(e4h.z); ev[3] = bf2f(e4h.w);
        }
        #pragma unroll
        for (int q = 0; q < 4; ++q) {
            const int dd = c0 + q;
            const int sw = (dd & 7) << 2;
            HT[dd * EMB + (d ^ sw)] = hv[q];
            GT[dd * EMB + (d ^ sw)] = ev[q] * (hv[q] - ev[q]);
        }
    }
    __syncthreads();

    const int tr = t >> 4;
    const int to = t & 15;

    float acc[4][4];
    #pragma unroll
    for (int i2 = 0; i2 < 4; ++i2)
        #pragma unroll
        for (int j2 = 0; j2 < 4; ++j2) acc[i2][j2] = 0.f;

    #pragma unroll 8
    for (int d = 0; d < EMB; ++d) {
        const int sw = (d & 7) << 2;
        const float4 ah4 = *(const float4*)&HT[d * EMB + ((tr * 4) ^ sw)];
        const float4 ag4 = *(const float4*)&GT[d * EMB + ((tr * 4) ^ sw)];
        const float4 wg4 = *(const float4*)&WG[d * EMB + to * 4];
        const float4 wb4 = *(const float4*)&WB[d * EMB + to * 4];
        const float ah[4] = {ah4.x, ah4.y, ah4.z, ah4.w};
        const float ag[4] = {ag4.x, ag4.y, ag4.z, ag4.w};
        const float wg[4] = {wg4.x, wg4.y, wg4.z, wg4.w};
        const float wb[4] = {wb4.x, wb4.y, wb4.z, wb4.w};
        #pragma unroll
        for (int i2 = 0; i2 < 4; ++i2)
            #pragma unroll
            for (int j2 = 0; j2 < 4; ++j2)
                acc[i2][j2] += ah[i2] * wg[j2] + ag[i2] * wb[j2];
    }

    const float4 bg4 = ((const float4*)bgc)[to];
    const float4 bb4 = ((const float4*)bbi)[to];
    const float bs[4] = {bg4.x + bb4.x, bg4.y + bb4.y, bg4.z + bb4.z, bg4.w + bb4.w};

    #pragma unroll
    for (int i2 = 0; i2 < 4; ++i2) {
        const int gr = r0 + tr * 4 + i2;
        if (gr < N_NODES) {
            ushort4 h;
            float v0 = acc[i2][0] + bs[0];
            float v1 = acc[i2][1] + bs[1];
            float v2 = acc[i2][2] + bs[2];
            float v3 = acc[i2][3] + bs[3];
            v0 = (v0 >= 0.f) ? v0 : 0.01f * v0;
            v1 = (v1 >= 0.f) ? v1 : 0.01f * v1;
            v2 = (v2 >= 0.f) ? v2 : 0.01f * v2;
            v3 = (v3 >= 0.f) ? v3 : 0.01f * v3;
            h.x = f2bf(v0); h.y = f2bf(v1); h.z = f2bf(v2); h.w = f2bf(v3);
            *(ushort4*)&ego16[(size_t)gr * EMB + to * 4] = h;
        }
    }
}

// ---------------------------------------------------------------------------
// gather + per-row L2 normalize for the 3*BATCH needed rows of this layer
// ---------------------------------------------------------------------------
__global__ __launch_bounds__(256) void gather_norm(const unsigned short* __restrict__ ego16,
                                                   const int* __restrict__ u,
                                                   const int* __restrict__ ii,
                                                   const int* __restrict__ jj,
                                                   float* __restrict__ Gk) {
    const int gtid = blockIdx.x * blockDim.x + threadIdx.x;
    const int wave = gtid >> 6;
    const int lane = threadIdx.x & 63;
    if (wave >= 3 * BATCH) return;
    const int a = wave / BATCH;
    const int b = wave - a * BATCH;
    const int node = (a == 0) ? u[b] : N_USERS + ((a == 1) ? ii[b] : jj[b]);
    const float v = bf2f(ego16[(size_t)node * EMB + lane]);
    float ss = v * v;
    #pragma unroll
    for (int m = 32; m; m >>= 1) ss += __shfl_xor(ss, m);
    const float inv = 1.f / fmaxf(sqrtf(ss), 1e-12f);
    Gk[(size_t)wave * EMB + lane] = v * inv;
}

// ---------------------------------------------------------------------------
// BPR loss + L2 reg: stage 1 — per-block partials (no global atomics)
// ---------------------------------------------------------------------------
__global__ __launch_bounds__(256) void loss_partial(const float* __restrict__ ue,
                                                    const float* __restrict__ ie,
                                                    const float* __restrict__ G,
                                                    const int* __restrict__ u,
                                                    const int* __restrict__ ii,
                                                    const int* __restrict__ jj,
                                                    float* __restrict__ partial) {
    __shared__ float wsum[4];
    const int t    = threadIdx.x;
    const int lane = t & 63;
    const int w    = t >> 6;                 // wave 0..3

    float sum = 0.f;                          // wave-uniform accumulator
    #pragma unroll
    for (int s = 0; s < LSPB / 4; ++s) {
        const int b = blockIdx.x * LSPB + w * (LSPB / 4) + s;
        const int uu = u[b], pi = ii[b], nj = jj[b];
        float uv[4], pv[4], nv[4];
        uv[0] = ue[(size_t)uu * EMB + lane];
        pv[0] = ie[(size_t)pi * EMB + lane];
        nv[0] = ie[(size_t)nj * EMB + lane];
        #pragma unroll
        for (int k = 0; k < 3; ++k) {
            uv[k + 1] = G[(((size_t)k * 3 + 0) * BATCH + b) * EMB + lane];
            pv[k + 1] = G[(((size_t)k * 3 + 1) * BATCH + b) * EMB + lane];
            nv[k + 1] = G[(((size_t)k * 3 + 2) * BATCH + b) * EMB + lane];
        }
        float yui = 0.f, yuj = 0.f, l2 = 0.f;
        #pragma unroll
        for (int q = 0; q < 4; ++q) {
            yui += uv[q] * pv[q];
            yuj += uv[q] * nv[q];
            l2  += uv[q] * uv[q] + pv[q] * pv[q] + nv[q] * nv[q];
        }
        #pragma unroll
        for (int m = 32; m; m >>= 1) {
            yui += __shfl_xor(yui, m);
            yuj += __shfl_xor(yuj, m);
            l2  += __shfl_xor(l2, m);
        }
        const float d  = yui - yuj;
        const float sp = (d > 0.f) ? log1pf(expf(-d)) : (-d + log1pf(expf(d)));
        sum += sp * (1.f / BATCH) + REG_C * (l2 * 0.5f) * (1.f / BATCH);
    }
    if (lane == 0) wsum[w] = sum;
    __syncthreads();
    if (t == 0) partial[blockIdx.x] = wsum[0] + wsum[1] + wsum[2] + wsum[3];
}

// ---------------------------------------------------------------------------
// stage 2 — one block sums the 256 partials, writes out[0]
// ---------------------------------------------------------------------------
__global__ __launch_bounds__(256) void final_reduce(const float* __restrict__ partial,
                                                    float* __restrict__ out) {
    __shared__ float wsum[4];
    const int t = threadIdx.x;
    const int lane = t & 63, w = t >> 6;
    float v = partial[t];
    #pragma unroll
    for (int m = 32; m; m >>= 1) v += __shfl_xor(v, m);
    if (lane == 0) wsum[w] = v;
    __syncthreads();
    if (t == 0) out[0] = wsum[0] + wsum[1] + wsum[2] + wsum[3];
}

// ---------------------------------------------------------------------------
extern "C" void kernel_launch(void* const* d_in, const int* in_sizes, int n_in,
                              void* d_out, int out_size, void* d_ws, size_t ws_size,
                              hipStream_t stream) {
    const float* ue   = (const float*)d_in[0];
    const float* ie   = (const float*)d_in[1];
    const float* Wgc  = (const float*)d_in[2];
    const float* bgc  = (const float*)d_in[3];
    const float* Wbi  = (const float*)d_in[4];
    const float* bbi  = (const float*)d_in[5];
    const float* aval = (const float*)d_in[6];
    const int*   arow = (const int*)d_in[7];
    const int*   acol = (const int*)d_in[8];
    const int*   u    = (const int*)d_in[9];
    const int*   ii   = (const int*)d_in[10];
    const int*   jj   = (const int*)d_in[11];
    float* out = (float*)d_out;

    const size_t NE = (size_t)N_NODES * EMB;            // 6.4M elements
    char* p = (char*)d_ws;
    unsigned short* ego16  = (unsigned short*)p;  p += NE * 2;                  // 12.8 MB
    unsigned short* side16 = (unsigned short*)p;  p += NE * 2;                  // 12.8 MB
    float* G     = (float*)p;                 p += (size_t)9 * BATCH * EMB * 4; // 9.4 MB
    float* lpart = (float*)p;                 p += (size_t)LNB * 4;
    int* row_ptr = (int*)p;                   p += (size_t)(N_NODES + 2) * 4;
    int* bcnt    = (int*)p;                   p += (size_t)(NBUCK + 1) * 4;
    int* bbase   = (int*)p;                   p += (size_t)(NBUCK + 1) * 4;
    p = (char*)(((uintptr_t)p + 15) & ~(uintptr_t)15);
    int2* epack  = (int2*)p;                  p += (size_t)NNZ_E * 8;           // 12.8 MB
    int2* bin    = (int2*)p;                  p += (size_t)NBUCK * BCAP * 8;    // 16.0 MB

    // ---- build bucketed, col-sorted CSR once -----------------------------
    hipMemsetAsync(bcnt, 0, (NBUCK + 1) * sizeof(int), stream);
    hipLaunchKernelGGL(binscatter, dim3(NSB), dim3(256), 0, stream,
                       arow, acol, aval, bcnt, bin);
    hipLaunchKernelGGL(scan_buckets, dim3(1), dim3(512), 0, stream, bcnt, bbase);
    hipLaunchKernelGGL(colsort_place, dim3(NBUCK), dim3(256), 0, stream,
                       bcnt, bin);
    hipLaunchKernelGGL(csr_place, dim3(NBUCK), dim3(256), 0, stream,
                       bcnt, bbase, bin, row_ptr, epack);

    hipLaunchKernelGGL(init_ego, dim3(2048), dim3(256), 0, stream, ue, ie, ego16);

    for (int k = 0; k < 3; ++k) {
        hipLaunchKernelGGL(spmm_csr, dim3((N_NODES * 64 + 255) / 256), dim3(256), 0, stream,
                           row_ptr, epack, ego16, side16);
        hipLaunchKernelGGL(layer_update, dim3((N_NODES + 63) / 64), dim3(256), 0, stream,
                           side16, ego16,
                           Wgc + (size_t)k * EMB * EMB, bgc + (size_t)k * EMB,
                           Wbi + (size_t)k * EMB * EMB, bbi + (size_t)k * EMB);
        hipLaunchKernelGGL(gather_norm, dim3((3 * BATCH + 3) / 4), dim3(256), 0, stream,
                           ego16, u, ii, jj, G + (size_t)k * 3 * BATCH * EMB);
    }

    hipLaunchKernelGGL(loss_partial, dim3(LNB), dim3(256), 0, stream,
                       ue, ie, G, u, ii, jj, lpart);
    hipLaunchKernelGGL(final_reduce, dim3(1), dim3(256), 0, stream, lpart, out);
}

// Round 11
// 466.606 us; speedup vs baseline: 5.0804x; 1.0240x over previous
//
#include <hip/hip_runtime.h>
#include <math.h>

#define N_USERS 50000
#define N_ITEMS 50000
#define N_NODES 100000
#define NNZ_E   1600000
#define EMB     64
#define BATCH   4096
#define REG_C   1e-5f

// bucketed geometry
#define BSH    8                                  // 256 rows per bucket
#define NBUCK  ((N_NODES + 255) >> BSH)           // 391
#define BCAP   5120                               // mean 4096 + 16 sigma slack
#define NSB    256                                // binning blocks
#define CHUNK  ((NNZ_E + NSB - 1) / NSB)          // 6250 edges per block

// loss reduction geometry
#define LNB    256                                // partial blocks
#define LSPB   (BATCH / LNB)                      // 16 samples per block

__device__ __forceinline__ unsigned short f2bf(float f) {
    unsigned u = __float_as_uint(f);
    u = (u + 0x7FFFu + ((u >> 16) & 1u)) >> 16;   // round-to-nearest-even
    return (unsigned short)u;
}
__device__ __forceinline__ float bf2f(unsigned short h) {
    return __uint_as_float(((unsigned)h) << 16);
}

// ---------------------------------------------------------------------------
// ego16 = bf16(concat(user_emb, item_emb))
// ---------------------------------------------------------------------------
__global__ __launch_bounds__(256) void init_ego(const float* __restrict__ ue,
                                                const float* __restrict__ ie,
                                                unsigned short* __restrict__ ego16) {
    const int total = N_NODES * EMB / 4;      // float4 count
    const int uf4   = N_USERS * EMB / 4;
    for (int idx = blockIdx.x * blockDim.x + threadIdx.x; idx < total;
         idx += gridDim.x * blockDim.x) {
        float4 v = (idx < uf4) ? ((const float4*)ue)[idx]
                               : ((const float4*)ie)[idx - uf4];
        ushort4 h;
        h.x = f2bf(v.x); h.y = f2bf(v.y); h.z = f2bf(v.z); h.w = f2bf(v.w);
        *(ushort4*)&ego16[(size_t)idx * 4] = h;
    }
}

// ---------------------------------------------------------------------------
// Pass 1: bin edges by 256-row bucket.
// bin entry: ( (row&255)<<17 | col , val_bits )
// ---------------------------------------------------------------------------
__global__ __launch_bounds__(256) void binscatter(const int* __restrict__ rw,
                                                  const int* __restrict__ cl,
                                                  const float* __restrict__ val,
                                                  int* __restrict__ bcnt,
                                                  int2* __restrict__ bin) {
    __shared__ int lcount[NBUCK];
    __shared__ int lbase[NBUCK];
    const int t    = threadIdx.x;
    const int eend = min(NNZ_E, (int)((blockIdx.x + 1) * CHUNK));

    for (int b = t; b < NBUCK; b += 256) lcount[b] = 0;
    __syncthreads();

    for (int e = blockIdx.x * CHUNK + t; e < eend; e += 256)
        atomicAdd(&lcount[rw[e] >> BSH], 1);
    __syncthreads();

    for (int b = t; b < NBUCK; b += 256) {
        const int c = lcount[b];
        lbase[b]  = (c > 0) ? atomicAdd(&bcnt[b], c) : 0;
        lcount[b] = 0;
    }
    __syncthreads();

    for (int e = blockIdx.x * CHUNK + t; e < eend; e += 256) {
        const int r = rw[e];
        const int b = r >> BSH;
        const int ofs = atomicAdd(&lcount[b], 1);
        const int rel = lbase[b] + ofs;
        if (rel < BCAP)
            bin[(size_t)b * BCAP + rel] =
                make_int2(((r & 255) << 17) | cl[e], __float_as_int(val[e]));
    }
}

// ---------------------------------------------------------------------------
// Exclusive scan of the 391 bucket counts
// ---------------------------------------------------------------------------
__global__ __launch_bounds__(512) void scan_buckets(const int* __restrict__ bcnt,
                                                    int* __restrict__ bbase) {
    const int t = threadIdx.x;
    const int lane = t & 63, w = t >> 6;
    const int v = (t < NBUCK) ? bcnt[t] : 0;
    int incl = v;
    #pragma unroll
    for (int off = 1; off < 64; off <<= 1) {
        const int x = __shfl_up(incl, off);
        if (lane >= off) incl += x;
    }
    __shared__ int wt[8];
    if (lane == 63) wt[w] = incl;
    __syncthreads();
    int wb = 0;
    #pragma unroll
    for (int q = 0; q < 8; ++q) wb += (q < w) ? wt[q] : 0;
    if (t < NBUCK) bbase[t] = wb + incl - v;
}

// ---------------------------------------------------------------------------
// Pass 2a: per-bucket counting sort by col>>9 (L2 gather locality)
// ---------------------------------------------------------------------------
__global__ __launch_bounds__(256) void colsort_place(const int* __restrict__ bcnt,
                                                     int2* __restrict__ bin) {
    __shared__ int2 ebuf[BCAP];          // 40 KB
    __shared__ int  cnt[256];
    __shared__ int  wt[4];
    const int t    = threadIdx.x;
    const int buck = blockIdx.x;
    const int n    = min(bcnt[buck], BCAP);
    int2* mybin = bin + (size_t)buck * BCAP;

    cnt[t] = 0;
    for (int i = t; i < n; i += 256) ebuf[i] = mybin[i];
    __syncthreads();

    for (int i = t; i < n; i += 256)
        atomicAdd(&cnt[(ebuf[i].x & 0x1FFFF) >> 9], 1);   // key 0..195
    __syncthreads();

    const int c    = cnt[t];
    const int lane = t & 63, w = t >> 6;
    int incl = c;
    #pragma unroll
    for (int off = 1; off < 64; off <<= 1) {
        const int v = __shfl_up(incl, off);
        if (lane >= off) incl += v;
    }
    if (lane == 63) wt[w] = incl;
    __syncthreads();
    int wb = 0;
    #pragma unroll
    for (int q = 0; q < 4; ++q) wb += (q < w) ? wt[q] : 0;
    cnt[t] = wb + incl - c;              // exclusive base per key
    __syncthreads();

    for (int i = t; i < n; i += 256) {
        const int2 e   = ebuf[i];
        const int  pos = atomicAdd(&cnt[(e.x & 0x1FFFF) >> 9], 1);
        mybin[pos] = e;
    }
}

// ---------------------------------------------------------------------------
// Pass 2b: place edges at exact CSR positions (col-sorted within rows)
// ---------------------------------------------------------------------------
__global__ __launch_bounds__(256) void csr_place(const int* __restrict__ bcnt,
                                                 const int* __restrict__ bbase,
                                                 const int2* __restrict__ bin,
                                                 int* __restrict__ row_ptr,
                                                 int2* __restrict__ ep) {
    __shared__ int rcnt[256];
    __shared__ int rbase[256];
    __shared__ int wt[4];
    const int t    = threadIdx.x;
    const int buck = blockIdx.x;
    const int n    = min(bcnt[buck], BCAP);
    const int base = bbase[buck];
    const int2* mybin = bin + (size_t)buck * BCAP;

    rcnt[t] = 0;
    __syncthreads();
    for (int i = t; i < n; i += 256)
        atomicAdd(&rcnt[mybin[i].x >> 17], 1);
    __syncthreads();

    const int c = rcnt[t];
    const int lane = t & 63, w = t >> 6;
    int incl = c;
    #pragma unroll
    for (int off = 1; off < 64; off <<= 1) {
        const int x = __shfl_up(incl, off);
        if (lane >= off) incl += x;
    }
    if (lane == 63) wt[w] = incl;
    __syncthreads();
    int wb = 0;
    #pragma unroll
    for (int q = 0; q < 4; ++q) wb += (q < w) ? wt[q] : 0;
    const int myb = base + wb + incl - c;

    const int gr = (buck << BSH) + t;
    if (gr < N_NODES) row_ptr[gr] = myb;
    if (buck == 0 && t == 0) row_ptr[N_NODES] = NNZ_E;
    rbase[t] = myb;
    __syncthreads();
    rcnt[t] = 0;
    __syncthreads();

    for (int i = t; i < n; i += 256) {
        const int2 e  = mybin[i];
        const int r8  = e.x >> 17;
        const int col = e.x & 0x1FFFF;
        const int ofs = atomicAdd(&rcnt[r8], 1);
        ep[rbase[r8] + ofs] = make_int2(col, e.y);
    }
}

// ---------------------------------------------------------------------------
// CSR SpMM, edge-pair form: lanes 0-31 = even edges, 32-63 = odd edges.
// Each lane loads a dword (2 bf16 dims), bf16->f32 via shift/mask only.
// Final shfl_xor(32) combine, packed uint store by lanes 0-31.
// ---------------------------------------------------------------------------
__global__ __launch_bounds__(256) void spmm_csr(const int* __restrict__ rp,
                                                const int2* __restrict__ ep,
                                                const unsigned short* __restrict__ xb,
                                                unsigned short* __restrict__ y16) {
    const int w    = (blockIdx.x * blockDim.x + threadIdx.x) >> 6;
    const int l    = threadIdx.x & 63;
    const int sub  = l & 31;             // dim-pair index (dims 2*sub, 2*sub+1)
    const int half = l >> 5;             // edge parity
    if (w >= N_NODES) return;
    const int beg = rp[w];
    const int end = rp[w + 1];
    float a0 = 0.f, a1 = 0.f;
    int e = beg;
    for (; e + 8 <= end; e += 8) {       // 4 pairs per iteration
        int2 p[4];
        #pragma unroll
        for (int q = 0; q < 4; ++q) p[q] = ep[e + 2 * q + half];
        unsigned xv[4];
        #pragma unroll
        for (int q = 0; q < 4; ++q)
            xv[q] = *(const unsigned*)&xb[((size_t)p[q].x << 6) + (sub << 1)];
        #pragma unroll
        for (int q = 0; q < 4; ++q) {
            const float v = __int_as_float(p[q].y);
            a0 += v * __uint_as_float(xv[q] << 16);
            a1 += v * __uint_as_float(xv[q] & 0xFFFF0000u);
        }
    }
    for (; e + 2 <= end; e += 2) {
        const int2 pq = ep[e + half];
        const unsigned xv = *(const unsigned*)&xb[((size_t)pq.x << 6) + (sub << 1)];
        const float v = __int_as_float(pq.y);
        a0 += v * __uint_as_float(xv << 16);
        a1 += v * __uint_as_float(xv & 0xFFFF0000u);
    }
    if (e < end) {                        // tail edge: only half==0 contributes
        const int2 pq = ep[e];
        const unsigned xv = *(const unsigned*)&xb[((size_t)pq.x << 6) + (sub << 1)];
        const float v = half ? 0.f : __int_as_float(pq.y);
        a0 += v * __uint_as_float(xv << 16);
        a1 += v * __uint_as_float(xv & 0xFFFF0000u);
    }
    a0 += __shfl_xor(a0, 32);
    a1 += __shfl_xor(a1, 32);
    if (half == 0) {
        const unsigned outp = (unsigned)f2bf(a0) | ((unsigned)f2bf(a1) << 16);
        ((unsigned*)y16)[((size_t)w << 5) + sub] = outp;
    }
}

// ---------------------------------------------------------------------------
// Fused: ego = leaky_relu(side @ Wgc + bgc + (ego*(side-ego)) @ Wbi + bbi)
// 512 threads/block (16 waves/CU at 64KB LDS), 64-row tile, bf16 in/out.
// ---------------------------------------------------------------------------
__global__ __launch_bounds__(512) void layer_update(const unsigned short* __restrict__ side16,
                                                    unsigned short* __restrict__ ego16,
                                                    const float* __restrict__ Wgc,
                                                    const float* __restrict__ bgc,
                                                    const float* __restrict__ Wbi,
                                                    const float* __restrict__ bbi) {
    __shared__ float HT[EMB * EMB];   // HT[d][r^sw]  (h = side)
    __shared__ float GT[EMB * EMB];   // GT[d][r^sw]  (g = ego*(side-ego))
    __shared__ float WG[EMB * EMB];   // WG[d][o]
    __shared__ float WB[EMB * EMB];   // WB[d][o]

    const int t  = threadIdx.x;
    const int r0 = blockIdx.x * 64;

    #pragma unroll
    for (int it = 0; it < 2; ++it) {
        const int f4  = t + it * 512;          // 0..1023
        const int d   = f4 >> 4;               // W row / tile row
        const int c0  = (f4 & 15) * 4;         // starting col

        float4 wg = ((const float4*)Wgc)[f4];
        float4 wb = ((const float4*)Wbi)[f4];
        *(float4*)&WG[d * EMB + c0] = wg;
        *(float4*)&WB[d * EMB + c0] = wb;

        const int gr = r0 + d;
        float hv[4] = {0.f, 0.f, 0.f, 0.f};
        float ev[4] = {0.f, 0.f, 0.f, 0.f};
        if (gr < N_NODES) {
            const ushort4 s4h = *(const ushort4*)&side16[(size_t)gr * EMB + c0];
            const ushort4 e4h = *(const ushort4*)&ego16[(size_t)gr * EMB + c0];
            hv[0] = bf2f(s4h.x); hv[1] = bf2f(s4h.y); hv[2] = bf2f(s4h.z); hv[3] = bf2f(s4h.w);
            ev[0] = bf2f(e4h.x); ev[1] = bf2f(e4h.y); ev[2] = bf2f(e4h.z); ev[3] = bf2f(e4h.w);
        }
        #pragma unroll
        for (int q = 0; q < 4; ++q) {
            const int dd = c0 + q;
            const int sw = (dd & 7) << 2;
            HT[dd * EMB + (d ^ sw)] = hv[q];
            GT[dd * EMB + (d ^ sw)] = ev[q] * (hv[q] - ev[q]);
        }
    }
    __syncthreads();

    const int tr = t >> 5;        // 0..15 -> rows 4tr..4tr+3
    const int to = t & 31;        // 0..31 -> cols 2to, 2to+1

    float acc[4][2];
    #pragma unroll
    for (int i2 = 0; i2 < 4; ++i2) { acc[i2][0] = 0.f; acc[i2][1] = 0.f; }

    #pragma unroll 8
    for (int d = 0; d < EMB; ++d) {
        const int sw = (d & 7) << 2;
        const float4 ah4 = *(const float4*)&HT[d * EMB + ((tr * 4) ^ sw)];
        const float4 ag4 = *(const float4*)&GT[d * EMB + ((tr * 4) ^ sw)];
        const float2 wg2 = *(const float2*)&WG[d * EMB + to * 2];
        const float2 wb2 = *(const float2*)&WB[d * EMB + to * 2];
        const float ah[4] = {ah4.x, ah4.y, ah4.z, ah4.w};
        const float ag[4] = {ag4.x, ag4.y, ag4.z, ag4.w};
        #pragma unroll
        for (int i2 = 0; i2 < 4; ++i2) {
            acc[i2][0] += ah[i2] * wg2.x + ag[i2] * wb2.x;
            acc[i2][1] += ah[i2] * wg2.y + ag[i2] * wb2.y;
        }
    }

    const float2 bg2 = *(const float2*)&bgc[to * 2];
    const float2 bb2 = *(const float2*)&bbi[to * 2];
    const float bs0 = bg2.x + bb2.x;
    const float bs1 = bg2.y + bb2.y;

    #pragma unroll
    for (int i2 = 0; i2 < 4; ++i2) {
        const int gr = r0 + tr * 4 + i2;
        if (gr < N_NODES) {
            float v0 = acc[i2][0] + bs0;
            float v1 = acc[i2][1] + bs1;
            v0 = (v0 >= 0.f) ? v0 : 0.01f * v0;
            v1 = (v1 >= 0.f) ? v1 : 0.01f * v1;
            const unsigned outp = (unsigned)f2bf(v0) | ((unsigned)f2bf(v1) << 16);
            ((unsigned*)ego16)[(size_t)gr * 32 + to] = outp;
        }
    }
}

// ---------------------------------------------------------------------------
// gather + per-row L2 normalize for the 3*BATCH needed rows of this layer
// ---------------------------------------------------------------------------
__global__ __launch_bounds__(256) void gather_norm(const unsigned short* __restrict__ ego16,
                                                   const int* __restrict__ u,
                                                   const int* __restrict__ ii,
                                                   const int* __restrict__ jj,
                                                   float* __restrict__ Gk) {
    const int gtid = blockIdx.x * blockDim.x + threadIdx.x;
    const int wave = gtid >> 6;
    const int lane = threadIdx.x & 63;
    if (wave >= 3 * BATCH) return;
    const int a = wave / BATCH;
    const int b = wave - a * BATCH;
    const int node = (a == 0) ? u[b] : N_USERS + ((a == 1) ? ii[b] : jj[b]);
    const float v = bf2f(ego16[(size_t)node * EMB + lane]);
    float ss = v * v;
    #pragma unroll
    for (int m = 32; m; m >>= 1) ss += __shfl_xor(ss, m);
    const float inv = 1.f / fmaxf(sqrtf(ss), 1e-12f);
    Gk[(size_t)wave * EMB + lane] = v * inv;
}

// ---------------------------------------------------------------------------
// BPR loss + L2 reg: stage 1 — per-block partials (no global atomics)
// ---------------------------------------------------------------------------
__global__ __launch_bounds__(256) void loss_partial(const float* __restrict__ ue,
                                                    const float* __restrict__ ie,
                                                    const float* __restrict__ G,
                                                    const int* __restrict__ u,
                                                    const int* __restrict__ ii,
                                                    const int* __restrict__ jj,
                                                    float* __restrict__ partial) {
    __shared__ float wsum[4];
    const int t    = threadIdx.x;
    const int lane = t & 63;
    const int w    = t >> 6;                 // wave 0..3

    float sum = 0.f;                          // wave-uniform accumulator
    #pragma unroll
    for (int s = 0; s < LSPB / 4; ++s) {
        const int b = blockIdx.x * LSPB + w * (LSPB / 4) + s;
        const int uu = u[b], pi = ii[b], nj = jj[b];
        float uv[4], pv[4], nv[4];
        uv[0] = ue[(size_t)uu * EMB + lane];
        pv[0] = ie[(size_t)pi * EMB + lane];
        nv[0] = ie[(size_t)nj * EMB + lane];
        #pragma unroll
        for (int k = 0; k < 3; ++k) {
            uv[k + 1] = G[(((size_t)k * 3 + 0) * BATCH + b) * EMB + lane];
            pv[k + 1] = G[(((size_t)k * 3 + 1) * BATCH + b) * EMB + lane];
            nv[k + 1] = G[(((size_t)k * 3 + 2) * BATCH + b) * EMB + lane];
        }
        float yui = 0.f, yuj = 0.f, l2 = 0.f;
        #pragma unroll
        for (int q = 0; q < 4; ++q) {
            yui += uv[q] * pv[q];
            yuj += uv[q] * nv[q];
            l2  += uv[q] * uv[q] + pv[q] * pv[q] + nv[q] * nv[q];
        }
        #pragma unroll
        for (int m = 32; m; m >>= 1) {
            yui += __shfl_xor(yui, m);
            yuj += __shfl_xor(yuj, m);
            l2  += __shfl_xor(l2, m);
        }
        const float d  = yui - yuj;
        const float sp = (d > 0.f) ? log1pf(expf(-d)) : (-d + log1pf(expf(d)));
        sum += sp * (1.f / BATCH) + REG_C * (l2 * 0.5f) * (1.f / BATCH);
    }
    if (lane == 0) wsum[w] = sum;
    __syncthreads();
    if (t == 0) partial[blockIdx.x] = wsum[0] + wsum[1] + wsum[2] + wsum[3];
}

// ---------------------------------------------------------------------------
// stage 2 — one block sums the 256 partials, writes out[0]
// ---------------------------------------------------------------------------
__global__ __launch_bounds__(256) void final_reduce(const float* __restrict__ partial,
                                                    float* __restrict__ out) {
    __shared__ float wsum[4];
    const int t = threadIdx.x;
    const int lane = t & 63, w = t >> 6;
    float v = partial[t];
    #pragma unroll
    for (int m = 32; m; m >>= 1) v += __shfl_xor(v, m);
    if (lane == 0) wsum[w] = v;
    __syncthreads();
    if (t == 0) out[0] = wsum[0] + wsum[1] + wsum[2] + wsum[3];
}

// ---------------------------------------------------------------------------
extern "C" void kernel_launch(void* const* d_in, const int* in_sizes, int n_in,
                              void* d_out, int out_size, void* d_ws, size_t ws_size,
                              hipStream_t stream) {
    const float* ue   = (const float*)d_in[0];
    const float* ie   = (const float*)d_in[1];
    const float* Wgc  = (const float*)d_in[2];
    const float* bgc  = (const float*)d_in[3];
    const float* Wbi  = (const float*)d_in[4];
    const float* bbi  = (const float*)d_in[5];
    const float* aval = (const float*)d_in[6];
    const int*   arow = (const int*)d_in[7];
    const int*   acol = (const int*)d_in[8];
    const int*   u    = (const int*)d_in[9];
    const int*   ii   = (const int*)d_in[10];
    const int*   jj   = (const int*)d_in[11];
    float* out = (float*)d_out;

    const size_t NE = (size_t)N_NODES * EMB;            // 6.4M elements
    char* p = (char*)d_ws;
    unsigned short* ego16  = (unsigned short*)p;  p += NE * 2;                  // 12.8 MB
    unsigned short* side16 = (unsigned short*)p;  p += NE * 2;                  // 12.8 MB
    float* G     = (float*)p;                 p += (size_t)9 * BATCH * EMB * 4; // 9.4 MB
    float* lpart = (float*)p;                 p += (size_t)LNB * 4;
    int* row_ptr = (int*)p;                   p += (size_t)(N_NODES + 2) * 4;
    int* bcnt    = (int*)p;                   p += (size_t)(NBUCK + 1) * 4;
    int* bbase   = (int*)p;                   p += (size_t)(NBUCK + 1) * 4;
    p = (char*)(((uintptr_t)p + 15) & ~(uintptr_t)15);
    int2* epack  = (int2*)p;                  p += (size_t)NNZ_E * 8;           // 12.8 MB
    int2* bin    = (int2*)p;                  p += (size_t)NBUCK * BCAP * 8;    // 16.0 MB

    // ---- build bucketed, col-sorted CSR once -----------------------------
    hipMemsetAsync(bcnt, 0, (NBUCK + 1) * sizeof(int), stream);
    hipLaunchKernelGGL(binscatter, dim3(NSB), dim3(256), 0, stream,
                       arow, acol, aval, bcnt, bin);
    hipLaunchKernelGGL(scan_buckets, dim3(1), dim3(512), 0, stream, bcnt, bbase);
    hipLaunchKernelGGL(colsort_place, dim3(NBUCK), dim3(256), 0, stream,
                       bcnt, bin);
    hipLaunchKernelGGL(csr_place, dim3(NBUCK), dim3(256), 0, stream,
                       bcnt, bbase, bin, row_ptr, epack);

    hipLaunchKernelGGL(init_ego, dim3(2048), dim3(256), 0, stream, ue, ie, ego16);

    for (int k = 0; k < 3; ++k) {
        hipLaunchKernelGGL(spmm_csr, dim3((N_NODES * 64 + 255) / 256), dim3(256), 0, stream,
                           row_ptr, epack, ego16, side16);
        hipLaunchKernelGGL(layer_update, dim3((N_NODES + 63) / 64), dim3(512), 0, stream,
                           side16, ego16,
                           Wgc + (size_t)k * EMB * EMB, bgc + (size_t)k * EMB,
                           Wbi + (size_t)k * EMB * EMB, bbi + (size_t)k * EMB);
        hipLaunchKernelGGL(gather_norm, dim3((3 * BATCH + 3) / 4), dim3(256), 0, stream,
                           ego16, u, ii, jj, G + (size_t)k * 3 * BATCH * EMB);
    }

    hipLaunchKernelGGL(loss_partial, dim3(LNB), dim3(256), 0, stream,
                       ue, ie, G, u, ii, jj, lpart);
    hipLaunchKernelGGL(final_reduce, dim3(1), dim3(256), 0, stream, lpart, out);
}